// Round 4
// baseline (394.702 us; speedup 1.0000x reference)
//
#include <hip/hip_runtime.h>

// Problem constants
#define BB 2
#define NN 4
#define DD 48
#define HH 28
#define WW 60
#define CC 64
#define NXg 192
#define NYg 192
#define NZg 1
#define DOWNS 8

constexpr int PTS    = BB * NN * DD * HH * WW;       // 645120 points
constexpr int NCELLS = BB * NZg * NYg * NXg;         // 73728 output cells
constexpr int CH_STRIDE = NYg * NXg;                 // 36864 floats per channel plane

// ---------------------------------------------------------------------------
// Kernel A: per-point geometry -> cell id (or -1); histogram atomic returns
// the point's rank within its cell (makes the reorder pass atomic-free).
// f64 to match the numpy f32 reference's cell assignment at boundaries
// (verified: absmax 0.125 << 1.39 threshold across rounds 1-3).
// ---------------------------------------------------------------------------
__global__ void geom_hist_kernel(const float* __restrict__ intr,
                                 const float* __restrict__ pose,
                                 int* __restrict__ sidx,
                                 int* __restrict__ rankv,
                                 int* __restrict__ counts) {
    int p = blockIdx.x * blockDim.x + threadIdx.x;   // grid is exact multiple
    int w = p % WW;
    int t = p / WW;
    int h = t % HH; t /= HH;
    int d = t % DD; t /= DD;
    int n = t % NN;
    int b = t / NN;

    const float* K  = intr + (size_t)(b * NN + n) * 9;
    const float* Pm = pose + (size_t)(b * NN + n) * 16;

    double k00 = K[0], k01 = K[1], k02 = K[2];
    double k10 = K[3], k11 = K[4], k12 = K[5];
    double k20 = K[6], k21 = K[7], k22 = K[8];

    double det = k00 * (k11 * k22 - k12 * k21)
               - k01 * (k10 * k22 - k12 * k20)
               + k02 * (k10 * k21 - k11 * k20);
    double id = 1.0 / det;
    double i00 = (k11 * k22 - k12 * k21) * id;
    double i01 = (k02 * k21 - k01 * k22) * id;
    double i02 = (k01 * k12 - k02 * k11) * id;
    double i10 = (k12 * k20 - k10 * k22) * id;
    double i11 = (k00 * k22 - k02 * k20) * id;
    double i12 = (k02 * k10 - k00 * k12) * id;
    double i20 = (k10 * k21 - k11 * k20) * id;
    double i21 = (k01 * k20 - k00 * k21) * id;
    double i22 = (k00 * k11 - k01 * k10) * id;

    double r00 = Pm[0],  r01 = Pm[1],  r02 = Pm[2],  tx = Pm[3];
    double r10 = Pm[4],  r11 = Pm[5],  r12 = Pm[6],  ty = Pm[7];
    double r20 = Pm[8],  r21 = Pm[9],  r22 = Pm[10], tz = Pm[11];

    double c00 = r00 * i00 + r01 * i10 + r02 * i20;
    double c01 = r00 * i01 + r01 * i11 + r02 * i21;
    double c02 = r00 * i02 + r01 * i12 + r02 * i22;
    double c10 = r10 * i00 + r11 * i10 + r12 * i20;
    double c11 = r10 * i01 + r11 * i11 + r12 * i21;
    double c12 = r10 * i02 + r11 * i12 + r12 * i22;
    double c20 = r20 * i00 + r21 * i10 + r22 * i20;
    double c21 = r20 * i01 + r21 * i11 + r22 * i21;
    double c22 = r20 * i02 + r21 * i12 + r22 * i22;

    double u   = (double)w * ((double)(WW * DOWNS - 1) / (double)(WW - 1));
    double v   = (double)h * ((double)(HH * DOWNS - 1) / (double)(HH - 1));
    double dep = 2.0 + (double)d;
    double px = u * dep, py = v * dep, pz = dep;

    double gxf = (c00 * px + c01 * py + c02 * pz + tx) * 4.0 + 96.0;
    double gyf = (c10 * px + c11 * py + c12 * pz + ty) * 4.0 + 96.0;
    double gzf = ((c20 * px + c21 * py + c22 * pz + tz) + 10.0) / 20.0;

    int gx = (int)gxf;
    int gy = (int)gyf;
    int gz = (int)gzf;

    bool kept = (gx >= 0) & (gx < NXg) & (gy >= 0) & (gy < NYg) &
                (gz >= 0) & (gz < NZg);

    int cell = kept ? (((b * NZg + gz) * NYg + gy) * NXg + gx) : -1;
    sidx[p] = cell;
    if (kept) rankv[p] = atomicAdd(&counts[cell], 1);
}

// ---------------------------------------------------------------------------
// Kernel B: single-block parallel scan (1024 thr x 72 cells each) producing
// exclusive offsets AND a compacted worklist of non-empty cells (sorted).
// Packed 64-bit scan: high bits = count prefix, low 24 bits = nonzero prefix.
// ---------------------------------------------------------------------------
__global__ void __launch_bounds__(1024)
scan_compact_kernel(const int* __restrict__ counts,
                    int* __restrict__ offsets,
                    int* __restrict__ worklist,
                    int* __restrict__ nwork) {
    __shared__ long long wsum[16];
    int tid  = threadIdx.x;
    int lane = tid & 63, wv = tid >> 6;
    constexpr int PER = NCELLS / 1024;       // 72
    int base = tid * PER;

    const int4* c4 = (const int4*)(counts + base);
    int localCnt = 0, localNZ = 0;
    #pragma unroll
    for (int j = 0; j < PER / 4; ++j) {
        int4 vv = c4[j];
        localCnt += vv.x + vv.y + vv.z + vv.w;
        localNZ  += (vv.x > 0) + (vv.y > 0) + (vv.z > 0) + (vv.w > 0);
    }

    long long packed = ((long long)localCnt << 24) | (long long)localNZ;
    long long incl = packed;
    #pragma unroll
    for (int o = 1; o < 64; o <<= 1) {
        long long tt = __shfl_up(incl, o, 64);
        if (lane >= o) incl += tt;
    }
    if (lane == 63) wsum[wv] = incl;
    __syncthreads();
    if (tid == 0) {
        long long run = 0;
        #pragma unroll
        for (int k = 0; k < 16; ++k) { long long tt = wsum[k]; wsum[k] = run; run += tt; }
    }
    __syncthreads();
    long long excl = wsum[wv] + incl - packed;
    int run = (int)(excl >> 24);
    int nz  = (int)(excl & 0xFFFFFF);

    #pragma unroll
    for (int j = 0; j < PER / 4; ++j) {
        int4 vv = c4[j];                      // L2-resident re-read
        int i0 = base + 4 * j;
        offsets[i0 + 0] = run; if (vv.x > 0) worklist[nz++] = i0 + 0; run += vv.x;
        offsets[i0 + 1] = run; if (vv.y > 0) worklist[nz++] = i0 + 1; run += vv.y;
        offsets[i0 + 2] = run; if (vv.z > 0) worklist[nz++] = i0 + 2; run += vv.z;
        offsets[i0 + 3] = run; if (vv.w > 0) worklist[nz++] = i0 + 3; run += vv.w;
    }
    if (tid == 1023) *nwork = nz;
}

// ---------------------------------------------------------------------------
// Kernel C: reorder the DATA (not ids) into cell-sorted order.
// One wave per point, lane = channel. Coalesced 256B read, coalesced 256B
// scattered write (stores are fire-and-forget; no latency chain to hide).
// ---------------------------------------------------------------------------
__global__ void reorder_kernel(const float* __restrict__ x,
                               const int* __restrict__ sidx,
                               const int* __restrict__ rankv,
                               const int* __restrict__ offsets,
                               float* __restrict__ xs) {
    int wave = blockIdx.x * (blockDim.x >> 6) + (threadIdx.x >> 6);
    int lane = threadIdx.x & 63;
    if (wave >= PTS) return;
    int cell = sidx[wave];       // broadcast load
    if (cell < 0) return;        // wave-uniform skip: culled rows never touched
    int dst = offsets[cell] + rankv[wave];
    xs[(size_t)dst * CC + lane] = x[(size_t)wave * CC + lane];
}

// ---------------------------------------------------------------------------
// Kernel D: block per non-empty cell (grid-stride over compacted worklist).
// Each cell's rows are now CONTIGUOUS in xs -> pure sequential streaming.
// 4 waves take contiguous quarters; 4 independent loads in flight per wave;
// LDS reduce; single coalesced-per-lane store.
// ---------------------------------------------------------------------------
__global__ void gather_kernel(const float* __restrict__ xs,
                              const int* __restrict__ counts,
                              const int* __restrict__ offsets,
                              const int* __restrict__ worklist,
                              const int* __restrict__ nwork,
                              float* __restrict__ out) {
    __shared__ float red[4][64];
    int lane = threadIdx.x & 63, wv = threadIdx.x >> 6;
    int n = *nwork;

    for (int j = blockIdx.x; j < n; j += gridDim.x) {
        int cell = worklist[j];
        int cnt  = counts[cell];
        const float* base = xs + (size_t)offsets[cell] * CC + lane;

        // contiguous quarter per wave
        int q = (cnt + 3) >> 2;
        int s = wv * q;
        int e = s + q; if (e > cnt) e = cnt;

        float a0 = 0.f, a1 = 0.f, a2 = 0.f, a3 = 0.f;
        float a4 = 0.f, a5 = 0.f, a6 = 0.f, a7 = 0.f;
        int k = s;
        for (; k + 8 <= e; k += 8) {
            a0 += base[(size_t)(k + 0) * CC];
            a1 += base[(size_t)(k + 1) * CC];
            a2 += base[(size_t)(k + 2) * CC];
            a3 += base[(size_t)(k + 3) * CC];
            a4 += base[(size_t)(k + 4) * CC];
            a5 += base[(size_t)(k + 5) * CC];
            a6 += base[(size_t)(k + 6) * CC];
            a7 += base[(size_t)(k + 7) * CC];
        }
        for (; k < e; ++k) a0 += base[(size_t)k * CC];

        red[wv][lane] = ((a0 + a1) + (a2 + a3)) + ((a4 + a5) + (a6 + a7));
        __syncthreads();
        if (wv == 0) {
            float sres = red[0][lane] + red[1][lane] + red[2][lane] + red[3][lane];
            int yx = cell % (NYg * NXg);
            int bz = cell / (NYg * NXg);
            out[((size_t)bz * CC + lane) * CH_STRIDE + yx] = sres;
        }
        __syncthreads();
    }
}

// ---------------------------------------------------------------------------
extern "C" void kernel_launch(void* const* d_in, const int* in_sizes, int n_in,
                              void* d_out, int out_size, void* d_ws, size_t ws_size,
                              hipStream_t stream) {
    const float* x    = (const float*)d_in[0];
    const float* intr = (const float*)d_in[1];
    const float* pose = (const float*)d_in[2];
    float* out = (float*)d_out;

    int* sidx     = (int*)d_ws;                // PTS
    int* rankv    = sidx + PTS;                // PTS
    int* counts   = rankv + PTS;               // NCELLS
    int* offsets  = counts + NCELLS;           // NCELLS
    int* worklist = offsets + NCELLS;          // NCELLS
    int* nwork    = worklist + NCELLS;         // 1
    float* xs     = (float*)(nwork + 1);       // up to PTS*CC floats (~165 MB)
    // total ws use: 2*PTS + 3*NCELLS + 1 ints + PTS*CC floats ~= 171 MB

    hipMemsetAsync(out, 0, (size_t)out_size * sizeof(float), stream);
    hipMemsetAsync(counts, 0, (size_t)NCELLS * sizeof(int), stream);

    geom_hist_kernel<<<PTS / 256, 256, 0, stream>>>(intr, pose, sidx, rankv, counts);
    scan_compact_kernel<<<1, 1024, 0, stream>>>(counts, offsets, worklist, nwork);
    reorder_kernel<<<PTS / 4, 256, 0, stream>>>(x, sidx, rankv, offsets, xs);
    gather_kernel<<<2048, 256, 0, stream>>>(xs, counts, offsets, worklist, nwork, out);
}

// Round 5
// 349.699 us; speedup vs baseline: 1.1287x; 1.1287x over previous
//
#include <hip/hip_runtime.h>

// Problem constants
#define BB 2
#define NN 4
#define DD 48
#define HH 28
#define WW 60
#define CC 64
#define NXg 192
#define NYg 192
#define NZg 1
#define DOWNS 8

constexpr int PTS    = BB * NN * DD * HH * WW;       // 645120 points
constexpr int NCELLS = BB * NZg * NYg * NXg;         // 73728 output cells
constexpr int CH_STRIDE = NYg * NXg;                 // 36864 floats per channel plane
constexpr int CHUNK = 64;                            // rows per gather work item
constexpr int MAXWORK = NCELLS + PTS / CHUNK + 64;   // worklist capacity

// ---------------------------------------------------------------------------
// Kernel A: per-point geometry -> cell id; block-local LDS hash aggregation
// so the global histogram sees ONE atomic per distinct (block, cell) instead
// of one per point (hot-cell chains drop ~450 -> ~28 deep).
// rank = global_base (from the one atomic) + LDS-local rank.
// f64 geometry matches the f32 numpy reference's cell assignment (absmax
// 0.125 << 1.39 across rounds 1-4).
// ---------------------------------------------------------------------------
__global__ void __launch_bounds__(256)
geom_hist_kernel(const float* __restrict__ intr,
                 const float* __restrict__ pose,
                 int* __restrict__ sidx,
                 int* __restrict__ rankv,
                 int* __restrict__ counts) {
    __shared__ int hkey[512];
    __shared__ int hval[512];
    __shared__ int hbase[512];

    int tid = threadIdx.x;
    for (int s = tid; s < 512; s += 256) { hkey[s] = -1; hval[s] = 0; }
    __syncthreads();

    int p = blockIdx.x * blockDim.x + tid;           // grid is exact multiple
    int w = p % WW;
    int t = p / WW;
    int h = t % HH; t /= HH;
    int d = t % DD; t /= DD;
    int n = t % NN;
    int b = t / NN;

    const float* K  = intr + (size_t)(b * NN + n) * 9;
    const float* Pm = pose + (size_t)(b * NN + n) * 16;

    double k00 = K[0], k01 = K[1], k02 = K[2];
    double k10 = K[3], k11 = K[4], k12 = K[5];
    double k20 = K[6], k21 = K[7], k22 = K[8];

    double det = k00 * (k11 * k22 - k12 * k21)
               - k01 * (k10 * k22 - k12 * k20)
               + k02 * (k10 * k21 - k11 * k20);
    double id = 1.0 / det;
    double i00 = (k11 * k22 - k12 * k21) * id;
    double i01 = (k02 * k21 - k01 * k22) * id;
    double i02 = (k01 * k12 - k02 * k11) * id;
    double i10 = (k12 * k20 - k10 * k22) * id;
    double i11 = (k00 * k22 - k02 * k20) * id;
    double i12 = (k02 * k10 - k00 * k12) * id;
    double i20 = (k10 * k21 - k11 * k20) * id;
    double i21 = (k01 * k20 - k00 * k21) * id;
    double i22 = (k00 * k11 - k01 * k10) * id;

    double r00 = Pm[0],  r01 = Pm[1],  r02 = Pm[2],  tx = Pm[3];
    double r10 = Pm[4],  r11 = Pm[5],  r12 = Pm[6],  ty = Pm[7];
    double r20 = Pm[8],  r21 = Pm[9],  r22 = Pm[10], tz = Pm[11];

    double c00 = r00 * i00 + r01 * i10 + r02 * i20;
    double c01 = r00 * i01 + r01 * i11 + r02 * i21;
    double c02 = r00 * i02 + r01 * i12 + r02 * i22;
    double c10 = r10 * i00 + r11 * i10 + r12 * i20;
    double c11 = r10 * i01 + r11 * i11 + r12 * i21;
    double c12 = r10 * i02 + r11 * i12 + r12 * i22;
    double c20 = r20 * i00 + r21 * i10 + r22 * i20;
    double c21 = r20 * i01 + r21 * i11 + r22 * i21;
    double c22 = r20 * i02 + r21 * i12 + r22 * i22;

    double u   = (double)w * ((double)(WW * DOWNS - 1) / (double)(WW - 1));
    double v   = (double)h * ((double)(HH * DOWNS - 1) / (double)(HH - 1));
    double dep = 2.0 + (double)d;
    double px = u * dep, py = v * dep, pz = dep;

    double gxf = (c00 * px + c01 * py + c02 * pz + tx) * 4.0 + 96.0;
    double gyf = (c10 * px + c11 * py + c12 * pz + ty) * 4.0 + 96.0;
    double gzf = ((c20 * px + c21 * py + c22 * pz + tz) + 10.0) / 20.0;

    int gx = (int)gxf;
    int gy = (int)gyf;
    int gz = (int)gzf;

    bool kept = (gx >= 0) & (gx < NXg) & (gy >= 0) & (gy < NYg) &
                (gz >= 0) & (gz < NZg);

    int cell = kept ? (((b * NZg + gz) * NYg + gy) * NXg + gx) : -1;
    sidx[p] = cell;

    // ---- LDS hash: slot per distinct cell in this block ----
    int slot = -1, lrank = 0;
    if (cell >= 0) {
        unsigned hsh = ((unsigned)cell * 2654435761u) >> 21;
        slot = (int)(hsh & 511u);
        while (true) {
            int prev = atomicCAS(&hkey[slot], -1, cell);
            if (prev == -1 || prev == cell) break;
            slot = (slot + 1) & 511;
        }
        lrank = atomicAdd(&hval[slot], 1);
    }
    __syncthreads();
    for (int s = tid; s < 512; s += 256) {
        int k = hkey[s];
        if (k >= 0) hbase[s] = atomicAdd(&counts[k], hval[s]);
    }
    __syncthreads();
    if (cell >= 0) rankv[p] = hbase[slot] + lrank;
}

// ---------------------------------------------------------------------------
// Kernel B: single-block parallel scan producing exclusive offsets AND a
// compacted worklist of (cell, 64-row chunk) work items, packed cell<<14|chunk.
// Packed 64-bit scan: high bits = count prefix, low 24 bits = chunk prefix.
// ---------------------------------------------------------------------------
__global__ void __launch_bounds__(1024)
scan_compact_kernel(const int* __restrict__ counts,
                    int* __restrict__ offsets,
                    int* __restrict__ worklist,
                    int* __restrict__ nwork) {
    __shared__ long long wsum[16];
    int tid  = threadIdx.x;
    int lane = tid & 63, wv = tid >> 6;
    constexpr int PER = NCELLS / 1024;       // 72
    int base = tid * PER;

    const int4* c4 = (const int4*)(counts + base);
    int localCnt = 0, localCh = 0;
    #pragma unroll
    for (int j = 0; j < PER / 4; ++j) {
        int4 vv = c4[j];
        localCnt += vv.x + vv.y + vv.z + vv.w;
        localCh  += ((vv.x + CHUNK - 1) >> 6) + ((vv.y + CHUNK - 1) >> 6)
                  + ((vv.z + CHUNK - 1) >> 6) + ((vv.w + CHUNK - 1) >> 6);
    }

    long long packed = ((long long)localCnt << 24) | (long long)localCh;
    long long incl = packed;
    #pragma unroll
    for (int o = 1; o < 64; o <<= 1) {
        long long tt = __shfl_up(incl, o, 64);
        if (lane >= o) incl += tt;
    }
    if (lane == 63) wsum[wv] = incl;
    __syncthreads();
    if (tid == 0) {
        long long run = 0;
        #pragma unroll
        for (int k = 0; k < 16; ++k) { long long tt = wsum[k]; wsum[k] = run; run += tt; }
    }
    __syncthreads();
    long long excl = wsum[wv] + incl - packed;
    int run = (int)(excl >> 24);
    int nw  = (int)(excl & 0xFFFFFF);

    for (int j = 0; j < PER; ++j) {
        int cellIdx = base + j;
        int v = counts[cellIdx];              // L2-resident re-read
        offsets[cellIdx] = run;
        run += v;
        int nch = (v + CHUNK - 1) >> 6;
        for (int c = 0; c < nch; ++c) worklist[nw++] = (cellIdx << 14) | c;
    }
    if (tid == 1023) *nwork = nw;
}

// ---------------------------------------------------------------------------
// Kernel C: atomic-free fill of bins (point ids) using precomputed ranks.
// Thread-per-point: 10k waves, cheap.
// ---------------------------------------------------------------------------
__global__ void fill_kernel(const int* __restrict__ sidx,
                            const int* __restrict__ rankv,
                            const int* __restrict__ offsets,
                            int* __restrict__ bins) {
    int p = blockIdx.x * blockDim.x + threadIdx.x;
    if (p >= PTS) return;
    int cell = sidx[p];
    if (cell < 0) return;
    bins[offsets[cell] + rankv[p]] = p;
}

// ---------------------------------------------------------------------------
// Kernel D: one wave per (cell, 64-row chunk). The 64 row ids arrive in ONE
// coalesced bins load (lane i = id i), then __shfl-broadcast drives 8-deep
// independent x-row loads (lane = channel). Partial sums combine via float
// atomicAdd (contention <= #chunks per cell, ~8 max). No dependent id->row
// chain, no hot-cell tail.
// ---------------------------------------------------------------------------
__global__ void __launch_bounds__(256)
gather_kernel(const float* __restrict__ x,
              const int* __restrict__ counts,
              const int* __restrict__ offsets,
              const int* __restrict__ bins,
              const int* __restrict__ worklist,
              const int* __restrict__ nwork,
              float* __restrict__ out) {
    int lane = threadIdx.x & 63;
    int gw   = blockIdx.x * (blockDim.x >> 6) + (threadIdx.x >> 6);
    int stride = gridDim.x * (blockDim.x >> 6);
    int n = *nwork;

    for (int j = gw; j < n; j += stride) {
        int e    = worklist[j];
        int cell = e >> 14;
        int ch   = e & 16383;
        int off  = offsets[cell] + (ch << 6);
        int m    = counts[cell] - (ch << 6);
        if (m > CHUNK) m = CHUNK;

        int bid = (lane < m) ? bins[off + lane] : 0;   // one coalesced load

        float a0 = 0.f, a1 = 0.f, a2 = 0.f, a3 = 0.f;
        float a4 = 0.f, a5 = 0.f, a6 = 0.f, a7 = 0.f;
        int i = 0;
        for (; i + 8 <= m; i += 8) {
            int p0 = __shfl(bid, i + 0);
            int p1 = __shfl(bid, i + 1);
            int p2 = __shfl(bid, i + 2);
            int p3 = __shfl(bid, i + 3);
            int p4 = __shfl(bid, i + 4);
            int p5 = __shfl(bid, i + 5);
            int p6 = __shfl(bid, i + 6);
            int p7 = __shfl(bid, i + 7);
            a0 += x[(size_t)p0 * CC + lane];
            a1 += x[(size_t)p1 * CC + lane];
            a2 += x[(size_t)p2 * CC + lane];
            a3 += x[(size_t)p3 * CC + lane];
            a4 += x[(size_t)p4 * CC + lane];
            a5 += x[(size_t)p5 * CC + lane];
            a6 += x[(size_t)p6 * CC + lane];
            a7 += x[(size_t)p7 * CC + lane];
        }
        for (; i < m; ++i) {
            int p0 = __shfl(bid, i);
            a0 += x[(size_t)p0 * CC + lane];
        }
        float s = ((a0 + a1) + (a2 + a3)) + ((a4 + a5) + (a6 + a7));

        int yx = cell % (NYg * NXg);
        int bz = cell / (NYg * NXg);
        atomicAdd(&out[((size_t)bz * CC + lane) * CH_STRIDE + yx], s);
    }
}

// ---------------------------------------------------------------------------
extern "C" void kernel_launch(void* const* d_in, const int* in_sizes, int n_in,
                              void* d_out, int out_size, void* d_ws, size_t ws_size,
                              hipStream_t stream) {
    const float* x    = (const float*)d_in[0];
    const float* intr = (const float*)d_in[1];
    const float* pose = (const float*)d_in[2];
    float* out = (float*)d_out;

    int* sidx     = (int*)d_ws;                // PTS
    int* rankv    = sidx + PTS;                // PTS
    int* counts   = rankv + PTS;               // NCELLS
    int* offsets  = counts + NCELLS;           // NCELLS
    int* worklist = offsets + NCELLS;          // MAXWORK
    int* nwork    = worklist + MAXWORK;        // 1
    int* bins     = nwork + 1;                 // PTS
    // total: 3*PTS + 2*NCELLS + MAXWORK + 1 ints ~= 8.7 MB

    hipMemsetAsync(out, 0, (size_t)out_size * sizeof(float), stream);
    hipMemsetAsync(counts, 0, (size_t)NCELLS * sizeof(int), stream);

    geom_hist_kernel<<<PTS / 256, 256, 0, stream>>>(intr, pose, sidx, rankv, counts);
    scan_compact_kernel<<<1, 1024, 0, stream>>>(counts, offsets, worklist, nwork);
    fill_kernel<<<(PTS + 255) / 256, 256, 0, stream>>>(sidx, rankv, offsets, bins);
    gather_kernel<<<1024, 256, 0, stream>>>(x, counts, offsets, bins, worklist, nwork, out);
}

// Round 6
// 257.256 us; speedup vs baseline: 1.5343x; 1.3593x over previous
//
#include <hip/hip_runtime.h>

// Problem constants
#define BB 2
#define NN 4
#define DD 48
#define HH 28
#define WW 60
#define CC 64
#define NXg 192
#define NYg 192
#define NZg 1
#define DOWNS 8

constexpr int PTS    = BB * NN * DD * HH * WW;       // 645120 points
constexpr int NCELLS = BB * NZg * NYg * NXg;         // 73728 output cells
constexpr int CH_STRIDE = NYg * NXg;                 // 36864 floats per channel plane
constexpr int CHUNK = 64;                            // rows per gather work item
constexpr int MAXWORK = NCELLS + PTS / CHUNK + 64;   // worklist capacity
constexpr int NBLK = NCELLS / 1024;                  // 72 scan blocks

// ---------------------------------------------------------------------------
// Kernel A: per-point geometry -> cell id; block-local LDS hash aggregation
// so the global histogram sees ONE atomic per distinct (block, cell).
// rank = global_base (from the one atomic) + LDS-local rank.
// f64 geometry matches the f32 numpy reference's cell assignment (absmax
// 0.125 << 1.39 across rounds 1-5).
// ---------------------------------------------------------------------------
__global__ void __launch_bounds__(256)
geom_hist_kernel(const float* __restrict__ intr,
                 const float* __restrict__ pose,
                 int* __restrict__ sidx,
                 int* __restrict__ rankv,
                 int* __restrict__ counts) {
    __shared__ int hkey[512];
    __shared__ int hval[512];
    __shared__ int hbase[512];

    int tid = threadIdx.x;
    for (int s = tid; s < 512; s += 256) { hkey[s] = -1; hval[s] = 0; }
    __syncthreads();

    int p = blockIdx.x * blockDim.x + tid;           // grid is exact multiple
    int w = p % WW;
    int t = p / WW;
    int h = t % HH; t /= HH;
    int d = t % DD; t /= DD;
    int n = t % NN;
    int b = t / NN;

    const float* K  = intr + (size_t)(b * NN + n) * 9;
    const float* Pm = pose + (size_t)(b * NN + n) * 16;

    double k00 = K[0], k01 = K[1], k02 = K[2];
    double k10 = K[3], k11 = K[4], k12 = K[5];
    double k20 = K[6], k21 = K[7], k22 = K[8];

    double det = k00 * (k11 * k22 - k12 * k21)
               - k01 * (k10 * k22 - k12 * k20)
               + k02 * (k10 * k21 - k11 * k20);
    double id = 1.0 / det;
    double i00 = (k11 * k22 - k12 * k21) * id;
    double i01 = (k02 * k21 - k01 * k22) * id;
    double i02 = (k01 * k12 - k02 * k11) * id;
    double i10 = (k12 * k20 - k10 * k22) * id;
    double i11 = (k00 * k22 - k02 * k20) * id;
    double i12 = (k02 * k10 - k00 * k12) * id;
    double i20 = (k10 * k21 - k11 * k20) * id;
    double i21 = (k01 * k20 - k00 * k21) * id;
    double i22 = (k00 * k11 - k01 * k10) * id;

    double r00 = Pm[0],  r01 = Pm[1],  r02 = Pm[2],  tx = Pm[3];
    double r10 = Pm[4],  r11 = Pm[5],  r12 = Pm[6],  ty = Pm[7];
    double r20 = Pm[8],  r21 = Pm[9],  r22 = Pm[10], tz = Pm[11];

    double c00 = r00 * i00 + r01 * i10 + r02 * i20;
    double c01 = r00 * i01 + r01 * i11 + r02 * i21;
    double c02 = r00 * i02 + r01 * i12 + r02 * i22;
    double c10 = r10 * i00 + r11 * i10 + r12 * i20;
    double c11 = r10 * i01 + r11 * i11 + r12 * i21;
    double c12 = r10 * i02 + r11 * i12 + r12 * i22;
    double c20 = r20 * i00 + r21 * i10 + r22 * i20;
    double c21 = r20 * i01 + r21 * i11 + r22 * i21;
    double c22 = r20 * i02 + r21 * i12 + r22 * i22;

    double u   = (double)w * ((double)(WW * DOWNS - 1) / (double)(WW - 1));
    double v   = (double)h * ((double)(HH * DOWNS - 1) / (double)(HH - 1));
    double dep = 2.0 + (double)d;
    double px = u * dep, py = v * dep, pz = dep;

    double gxf = (c00 * px + c01 * py + c02 * pz + tx) * 4.0 + 96.0;
    double gyf = (c10 * px + c11 * py + c12 * pz + ty) * 4.0 + 96.0;
    double gzf = ((c20 * px + c21 * py + c22 * pz + tz) + 10.0) / 20.0;

    int gx = (int)gxf;
    int gy = (int)gyf;
    int gz = (int)gzf;

    bool kept = (gx >= 0) & (gx < NXg) & (gy >= 0) & (gy < NYg) &
                (gz >= 0) & (gz < NZg);

    int cell = kept ? (((b * NZg + gz) * NYg + gy) * NXg + gx) : -1;
    sidx[p] = cell;

    // ---- LDS hash: slot per distinct cell in this block ----
    int slot = -1, lrank = 0;
    if (cell >= 0) {
        unsigned hsh = ((unsigned)cell * 2654435761u) >> 21;
        slot = (int)(hsh & 511u);
        while (true) {
            int prev = atomicCAS(&hkey[slot], -1, cell);
            if (prev == -1 || prev == cell) break;
            slot = (slot + 1) & 511;
        }
        lrank = atomicAdd(&hval[slot], 1);
    }
    __syncthreads();
    for (int s = tid; s < 512; s += 256) {
        int k = hkey[s];
        if (k >= 0) hbase[s] = atomicAdd(&counts[k], hval[s]);
    }
    __syncthreads();
    if (cell >= 0) rankv[p] = hbase[slot] + lrank;
}

// ---------------------------------------------------------------------------
// Kernel B1: per-block packed sums (count<<24 | nchunks). 72 blocks x 1024,
// thread-per-cell COALESCED loads (the round-5 single-block scan was a
// 104 us single-CU latency grind on stride-72 access).
// ---------------------------------------------------------------------------
__global__ void __launch_bounds__(1024)
blocksum_kernel(const int* __restrict__ counts,
                long long* __restrict__ blocksum) {
    __shared__ long long wsum[16];
    int tid = threadIdx.x, lane = tid & 63, wv = tid >> 6;
    int cell = blockIdx.x * 1024 + tid;
    int cnt = counts[cell];
    long long packed = ((long long)cnt << 24) | (long long)((cnt + 63) >> 6);
    #pragma unroll
    for (int o = 32; o > 0; o >>= 1) packed += __shfl_down(packed, o, 64);
    if (lane == 0) wsum[wv] = packed;
    __syncthreads();
    if (tid == 0) {
        long long s = 0;
        #pragma unroll
        for (int k = 0; k < 16; ++k) s += wsum[k];
        blocksum[blockIdx.x] = s;
    }
}

// ---------------------------------------------------------------------------
// Kernel B2: 72 blocks x 1024, thread-per-cell. Block base = serial sum of
// preceding blocksums (<=71 L2-hit loads by thread 0); block-wide
// shfl+LDS exclusive scan; coalesced offsets write; worklist chunk emission.
// ---------------------------------------------------------------------------
__global__ void __launch_bounds__(1024)
scan_emit_kernel(const int* __restrict__ counts,
                 const long long* __restrict__ blocksum,
                 int* __restrict__ offsets,
                 int* __restrict__ worklist,
                 int* __restrict__ nwork) {
    __shared__ long long wsum[16];
    __shared__ long long base_sh;
    int tid = threadIdx.x, lane = tid & 63, wv = tid >> 6;

    if (tid == 0) {
        long long s = 0;
        int nb = blockIdx.x;
        for (int j = 0; j < nb; ++j) s += blocksum[j];
        base_sh = s;
    }

    int cell = blockIdx.x * 1024 + tid;
    int cnt  = counts[cell];
    int nch  = (cnt + 63) >> 6;
    long long packed = ((long long)cnt << 24) | (long long)nch;

    long long incl = packed;
    #pragma unroll
    for (int o = 1; o < 64; o <<= 1) {
        long long tt = __shfl_up(incl, o, 64);
        if (lane >= o) incl += tt;
    }
    if (lane == 63) wsum[wv] = incl;
    __syncthreads();
    if (tid == 0) {
        long long run = 0;
        #pragma unroll
        for (int k = 0; k < 16; ++k) { long long tt = wsum[k]; wsum[k] = run; run += tt; }
    }
    __syncthreads();

    long long excl = base_sh + wsum[wv] + incl - packed;
    int off   = (int)(excl >> 24);
    int wbase = (int)(excl & 0xFFFFFF);

    offsets[cell] = off;
    for (int c = 0; c < nch; ++c) worklist[wbase + c] = (cell << 14) | c;
    if (blockIdx.x == NBLK - 1 && tid == 1023) *nwork = wbase + nch;
}

// ---------------------------------------------------------------------------
// Kernel C: atomic-free fill of bins (point ids) using precomputed ranks.
// ---------------------------------------------------------------------------
__global__ void fill_kernel(const int* __restrict__ sidx,
                            const int* __restrict__ rankv,
                            const int* __restrict__ offsets,
                            int* __restrict__ bins) {
    int p = blockIdx.x * blockDim.x + threadIdx.x;
    if (p >= PTS) return;
    int cell = sidx[p];
    if (cell < 0) return;
    bins[offsets[cell] + rankv[p]] = p;
}

// ---------------------------------------------------------------------------
// Kernel D: one wave per (cell, 64-row chunk). 64 row ids in ONE coalesced
// bins load, __shfl-broadcast drives 8-deep independent x-row loads
// (lane = channel). Partial sums combine via float atomicAdd (contention
// <= chunks/cell, ~8 max).
// ---------------------------------------------------------------------------
__global__ void __launch_bounds__(256)
gather_kernel(const float* __restrict__ x,
              const int* __restrict__ counts,
              const int* __restrict__ offsets,
              const int* __restrict__ bins,
              const int* __restrict__ worklist,
              const int* __restrict__ nwork,
              float* __restrict__ out) {
    int lane = threadIdx.x & 63;
    int gw   = blockIdx.x * (blockDim.x >> 6) + (threadIdx.x >> 6);
    int stride = gridDim.x * (blockDim.x >> 6);
    int n = *nwork;

    for (int j = gw; j < n; j += stride) {
        int e    = worklist[j];
        int cell = e >> 14;
        int ch   = e & 16383;
        int off  = offsets[cell] + (ch << 6);
        int m    = counts[cell] - (ch << 6);
        if (m > CHUNK) m = CHUNK;

        int bid = (lane < m) ? bins[off + lane] : 0;   // one coalesced load

        float a0 = 0.f, a1 = 0.f, a2 = 0.f, a3 = 0.f;
        float a4 = 0.f, a5 = 0.f, a6 = 0.f, a7 = 0.f;
        int i = 0;
        for (; i + 8 <= m; i += 8) {
            int p0 = __shfl(bid, i + 0);
            int p1 = __shfl(bid, i + 1);
            int p2 = __shfl(bid, i + 2);
            int p3 = __shfl(bid, i + 3);
            int p4 = __shfl(bid, i + 4);
            int p5 = __shfl(bid, i + 5);
            int p6 = __shfl(bid, i + 6);
            int p7 = __shfl(bid, i + 7);
            a0 += x[(size_t)p0 * CC + lane];
            a1 += x[(size_t)p1 * CC + lane];
            a2 += x[(size_t)p2 * CC + lane];
            a3 += x[(size_t)p3 * CC + lane];
            a4 += x[(size_t)p4 * CC + lane];
            a5 += x[(size_t)p5 * CC + lane];
            a6 += x[(size_t)p6 * CC + lane];
            a7 += x[(size_t)p7 * CC + lane];
        }
        for (; i < m; ++i) {
            int p0 = __shfl(bid, i);
            a0 += x[(size_t)p0 * CC + lane];
        }
        float s = ((a0 + a1) + (a2 + a3)) + ((a4 + a5) + (a6 + a7));

        int yx = cell % (NYg * NXg);
        int bz = cell / (NYg * NXg);
        atomicAdd(&out[((size_t)bz * CC + lane) * CH_STRIDE + yx], s);
    }
}

// ---------------------------------------------------------------------------
extern "C" void kernel_launch(void* const* d_in, const int* in_sizes, int n_in,
                              void* d_out, int out_size, void* d_ws, size_t ws_size,
                              hipStream_t stream) {
    const float* x    = (const float*)d_in[0];
    const float* intr = (const float*)d_in[1];
    const float* pose = (const float*)d_in[2];
    float* out = (float*)d_out;

    int* sidx       = (int*)d_ws;              // PTS
    int* rankv      = sidx + PTS;              // PTS
    int* counts     = rankv + PTS;             // NCELLS
    int* offsets    = counts + NCELLS;         // NCELLS
    long long* bsum = (long long*)(offsets + NCELLS);  // NBLK (8B-aligned: 2*PTS+2*NCELLS ints is even)
    int* worklist   = (int*)(bsum + NBLK);     // MAXWORK
    int* nwork      = worklist + MAXWORK;      // 1
    int* bins       = nwork + 1;               // PTS
    // total ~= 8.7 MB

    hipMemsetAsync(out, 0, (size_t)out_size * sizeof(float), stream);
    hipMemsetAsync(counts, 0, (size_t)NCELLS * sizeof(int), stream);

    geom_hist_kernel<<<PTS / 256, 256, 0, stream>>>(intr, pose, sidx, rankv, counts);
    blocksum_kernel<<<NBLK, 1024, 0, stream>>>(counts, bsum);
    scan_emit_kernel<<<NBLK, 1024, 0, stream>>>(counts, bsum, offsets, worklist, nwork);
    fill_kernel<<<(PTS + 255) / 256, 256, 0, stream>>>(sidx, rankv, offsets, bins);
    gather_kernel<<<1024, 256, 0, stream>>>(x, counts, offsets, bins, worklist, nwork, out);
}